// Round 1
// baseline (380.255 us; speedup 1.0000x reference)
//
#include <hip/hip_runtime.h>
#include <cstdint>
#include <cstddef>

#define NN 1024
#define BB 4
#define CC 256
#define HH 4
#define DD 64
#define EE 32768

// ---------- small prep kernels ----------

// WT[c*C + j] = W[j*C + c]
__global__ void k_transpose(const float* __restrict__ W, float* __restrict__ WT) {
    int j = blockIdx.x;
    int c = threadIdx.x;
    WT[c * CC + j] = W[j * CC + c];
}

// wsum[(l*H+h)*C + c] = (sum_d We_l[(h*D+d)*C + c]) * a_e_l[h]
__global__ void k_wsum(const float* __restrict__ We1, const float* __restrict__ ae1,
                       const float* __restrict__ We2, const float* __restrict__ ae2,
                       float* __restrict__ wsum) {
    int c = threadIdx.x;
    const float* We[2] = {We1, We2};
    const float* ae[2] = {ae1, ae2};
    for (int l = 0; l < 2; ++l)
        for (int h = 0; h < HH; ++h) {
            float s = 0.f;
            for (int d = 0; d < DD; ++d) s += We[l][(h * DD + d) * CC + c];
            wsum[(l * HH + h) * CC + c] = s * ae[l][h];
        }
}

// pe[l*E*H + e*H + h] = dot(edge_features[src[e], trg[e], :], wsum[l][h]) ; one wave per edge
__global__ void k_pe(const float* __restrict__ ef, const int* __restrict__ src,
                     const int* __restrict__ trg, const float* __restrict__ wsum,
                     float* __restrict__ pe) {
    __shared__ float wl[2 * HH * CC];
    int t = threadIdx.x;
    for (int i = t; i < 2 * HH * CC; i += 256) wl[i] = wsum[i];
    __syncthreads();
    int wid = t >> 6, lane = t & 63;
    int e = blockIdx.x * 4 + wid;
    int s = src[e], g = trg[e];
    const float* row = ef + ((long)s * NN + g) * CC;
    float4 v = *(const float4*)(row + lane * 4);
    float acc[8];
#pragma unroll
    for (int i = 0; i < 8; ++i) {
        const float* w = wl + i * CC + lane * 4;
        acc[i] = v.x * w[0] + v.y * w[1] + v.z * w[2] + v.w * w[3];
    }
#pragma unroll
    for (int off = 32; off; off >>= 1)
#pragma unroll
        for (int i = 0; i < 8; ++i) acc[i] += __shfl_down(acc[i], off, 64);
    if (lane == 0) {
#pragma unroll
        for (int i = 0; i < 8; ++i) {
            int l = i >> 2, h = i & 3;
            pe[(size_t)l * EE * HH + (size_t)e * HH + h] = acc[i];
        }
    }
}

// ---------- CSR build (counting sort by target) ----------

__global__ void k_count(const int* __restrict__ trg, int* __restrict__ counts) {
    int e = blockIdx.x * 256 + threadIdx.x;
    atomicAdd(&counts[trg[e]], 1);
}

__global__ void k_scan(const int* __restrict__ counts, int* __restrict__ rowptr,
                       int* __restrict__ fill) {
    __shared__ int sm[NN];
    int t = threadIdx.x;
    sm[t] = counts[t];
    __syncthreads();
    for (int off = 1; off < NN; off <<= 1) {
        int v = (t >= off) ? sm[t - off] : 0;
        __syncthreads();
        sm[t] += v;
        __syncthreads();
    }
    int excl = (t == 0) ? 0 : sm[t - 1];
    rowptr[t] = excl;
    fill[t] = excl;
    if (t == NN - 1) rowptr[NN] = sm[NN - 1];
}

__global__ void k_fill(const int* __restrict__ trg, int* __restrict__ fill,
                       int* __restrict__ edge_ids) {
    int e = blockIdx.x * 256 + threadIdx.x;
    int pos = atomicAdd(&fill[trg[e]], 1);
    edge_ids[pos] = e;
}

// sort each bucket ascending (determinism); one thread per node, deg ~32
__global__ void k_sort(const int* __restrict__ rowptr, int* __restrict__ edge_ids) {
    int n = blockIdx.x * 256 + threadIdx.x;
    if (n >= NN) return;
    int s = rowptr[n], e = rowptr[n + 1];
    for (int i = s + 1; i < e; ++i) {
        int v = edge_ids[i];
        int j = i - 1;
        while (j >= s && edge_ids[j] > v) { edge_ids[j + 1] = edge_ids[j]; --j; }
        edge_ids[j + 1] = v;
    }
}

// ---------- per-layer kernels ----------

#define ROWS 8
// h = x @ Wn.T via WT; fused per-node attention dots
__global__ void k_proj(const float* __restrict__ x, const float* __restrict__ WT,
                       const float* __restrict__ a_s, const float* __restrict__ a_t,
                       float* __restrict__ hout, float* __restrict__ alpha_s,
                       float* __restrict__ alpha_t) {
    __shared__ float xs[ROWS][CC];
    int t = threadIdx.x;
    int r0 = blockIdx.x * ROWS;
    for (int j = 0; j < ROWS; ++j) xs[j][t] = x[(size_t)(r0 + j) * CC + t];
    __syncthreads();
    float acc[ROWS];
#pragma unroll
    for (int j = 0; j < ROWS; ++j) acc[j] = 0.f;
    for (int c = 0; c < CC; ++c) {
        float w = WT[c * CC + t];
#pragma unroll
        for (int j = 0; j < ROWS; ++j) acc[j] += w * xs[j][c];
    }
    int h = t >> 6, d = t & 63;
    float as = a_s[h * DD + d], at = a_t[h * DD + d];
    for (int j = 0; j < ROWS; ++j) {
        hout[(size_t)(r0 + j) * CC + t] = acc[j];
        float vs = acc[j] * as, vt = acc[j] * at;
#pragma unroll
        for (int off = 32; off; off >>= 1) {
            vs += __shfl_down(vs, off, 64);
            vt += __shfl_down(vt, off, 64);
        }
        if (d == 0) {
            alpha_s[(size_t)(r0 + j) * HH + h] = vs;
            alpha_t[(size_t)(r0 + j) * HH + h] = vt;
        }
    }
}

// block = (n,b); wave = head; lane = d. Two passes over incoming edges.
__global__ void k_agg(const float* __restrict__ hbuf, const float* __restrict__ alpha_s,
                      const float* __restrict__ alpha_t, const float* __restrict__ pe_l,
                      const int* __restrict__ rowptr, const int* __restrict__ edge_ids,
                      const int* __restrict__ src, float* __restrict__ out) {
    int t = threadIdx.x;
    int hh = t >> 6, d = t & 63;
    int n = blockIdx.x >> 2;  // BB = 4
    int b = blockIdx.x & 3;
    int start = rowptr[n], end = rowptr[n + 1];
    float at_n = alpha_t[((size_t)n * BB + b) * HH + hh];
    // pass 1: denom (lanes parallel over edges)
    float denom = 0.f;
    for (int base = start; base < end; base += 64) {
        int i = base + d;
        float ex = 0.f;
        if (i < end) {
            int e = edge_ids[i];
            int s = src[e];
            float sc = alpha_s[((size_t)s * BB + b) * HH + hh] + at_n + pe_l[(size_t)e * HH + hh];
            sc = sc > 0.f ? sc : 0.2f * sc;
            ex = expf(sc);
        }
#pragma unroll
        for (int off = 32; off; off >>= 1) ex += __shfl_xor(ex, off, 64);
        denom += ex;
    }
    float inv = 1.f / (denom + 1e-16f);
    // pass 2: weighted aggregation (serial over edges, coalesced row loads)
    float acc = 0.f;
    for (int i = start; i < end; ++i) {
        int e = edge_ids[i];
        int s = src[e];
        float sc = alpha_s[((size_t)s * BB + b) * HH + hh] + at_n + pe_l[(size_t)e * HH + hh];
        sc = sc > 0.f ? sc : 0.2f * sc;
        float attn = expf(sc) * inv;
        acc += hbuf[((size_t)s * BB + b) * CC + hh * DD + d] * attn;
    }
    out[((size_t)n * BB + b) * CC + hh * DD + d] = acc;
}

// ---------- launch ----------

extern "C" void kernel_launch(void* const* d_in, const int* in_sizes, int n_in,
                              void* d_out, int out_size, void* d_ws, size_t ws_size,
                              hipStream_t stream) {
    const float* x   = (const float*)d_in[0];
    const float* ef  = (const float*)d_in[1];
    const int* src   = (const int*)d_in[2];
    const int* trg   = (const int*)d_in[3];
    const float* Wn1 = (const float*)d_in[4];
    const float* We1 = (const float*)d_in[5];
    const float* as1 = (const float*)d_in[6];
    const float* at1 = (const float*)d_in[7];
    const float* ae1 = (const float*)d_in[8];
    const float* Wn2 = (const float*)d_in[9];
    const float* We2 = (const float*)d_in[10];
    const float* as2 = (const float*)d_in[11];
    const float* at2 = (const float*)d_in[12];
    const float* ae2 = (const float*)d_in[13];
    float* out = (float*)d_out;

    float* wsf = (float*)d_ws;
    float* WnT1   = wsf;                    // 65536
    float* WnT2   = wsf + 65536;            // 65536
    float* wsum   = wsf + 131072;           // 2048
    float* pe     = wsf + 133120;           // 2*E*H = 262144
    float* hbuf   = wsf + 395264;           // N*B*C = 1048576
    float* alphas = wsf + 1443840;          // N*B*H = 16384
    float* alphat = wsf + 1460224;          // 16384
    float* x1     = wsf + 1476608;          // 1048576
    int*   iws    = (int*)(wsf + 2525184);
    int* rowptr   = iws;                    // N+1
    int* fill     = iws + 1028;             // N  (aligned)
    int* edge_ids = iws + 2052;             // E
    int* counts   = iws + 2052 + EE;        // N

    hipMemsetAsync(counts, 0, NN * sizeof(int), stream);

    k_transpose<<<CC, CC, 0, stream>>>(Wn1, WnT1);
    k_transpose<<<CC, CC, 0, stream>>>(Wn2, WnT2);
    k_wsum<<<1, CC, 0, stream>>>(We1, ae1, We2, ae2, wsum);
    k_pe<<<EE / 4, 256, 0, stream>>>(ef, src, trg, wsum, pe);

    k_count<<<EE / 256, 256, 0, stream>>>(trg, counts);
    k_scan<<<1, NN, 0, stream>>>(counts, rowptr, fill);
    k_fill<<<EE / 256, 256, 0, stream>>>(trg, fill, edge_ids);
    k_sort<<<(NN + 255) / 256, 256, 0, stream>>>(rowptr, edge_ids);

    // layer 1
    k_proj<<<(NN * BB) / ROWS, CC, 0, stream>>>(x, WnT1, as1, at1, hbuf, alphas, alphat);
    k_agg<<<NN * BB, 256, 0, stream>>>(hbuf, alphas, alphat, pe, rowptr, edge_ids, src, x1);
    // layer 2
    k_proj<<<(NN * BB) / ROWS, CC, 0, stream>>>(x1, WnT2, as2, at2, hbuf, alphas, alphat);
    k_agg<<<NN * BB, 256, 0, stream>>>(hbuf, alphas, alphat, pe + (size_t)EE * HH,
                                       rowptr, edge_ids, src, out);
}

// Round 3
// 149.443 us; speedup vs baseline: 2.5445x; 2.5445x over previous
//
#include <hip/hip_runtime.h>
#include <cstdint>
#include <cstddef>

#define NN 1024
#define BB 4
#define CC 256
#define HH 4
#define DD 64
#define EE 32768

// ---------- fused prep: Wn transposes + wsum ----------
// grid: [0,256) transpose Wn1 ; [256,512) transpose Wn2 ; [512,520) wsum(l,h)
__global__ void k_prep(const float* __restrict__ Wn1, const float* __restrict__ Wn2,
                       float* __restrict__ WnT1, float* __restrict__ WnT2,
                       const float* __restrict__ We1, const float* __restrict__ ae1,
                       const float* __restrict__ We2, const float* __restrict__ ae2,
                       float* __restrict__ wsum) {
    int bid = blockIdx.x, t = threadIdx.x;
    if (bid < 256) {
        WnT1[t * CC + bid] = Wn1[bid * CC + t];
    } else if (bid < 512) {
        int j = bid - 256;
        WnT2[t * CC + j] = Wn2[j * CC + t];
    } else {
        int idx = bid - 512;
        int l = idx >> 2, h = idx & 3;
        const float* We = l ? We2 : We1;
        const float* ae = l ? ae2 : ae1;
        float s = 0.f;
        for (int d = 0; d < DD; ++d) s += We[(h * DD + d) * CC + t];
        wsum[(l * HH + h) * CC + t] = s * ae[h];
    }
}

// ---------- CSR build: count + scan + fill in one single-block kernel ----------
__global__ void k_scanfill(const int* __restrict__ trg, int* __restrict__ rowptr,
                           int* __restrict__ edge_ids) {
    __shared__ int cnt[NN];
    __shared__ int pos[NN];
    int t = threadIdx.x;  // 1024 threads
    cnt[t] = 0;
    __syncthreads();
    for (int e = t; e < EE; e += NN) atomicAdd(&cnt[trg[e]], 1);
    __syncthreads();
    // Hillis-Steele inclusive scan
    for (int off = 1; off < NN; off <<= 1) {
        int v = (t >= off) ? cnt[t - off] : 0;
        __syncthreads();
        cnt[t] += v;
        __syncthreads();
    }
    int excl = (t == 0) ? 0 : cnt[t - 1];
    rowptr[t] = excl;
    pos[t] = excl;
    if (t == NN - 1) rowptr[NN] = cnt[NN - 1];
    __syncthreads();
    for (int e = t; e < EE; e += NN) {
        int p = atomicAdd(&pos[trg[e]], 1);
        edge_ids[p] = e;
    }
}

// ---------- deterministic in-bucket sort: one wave per node, rank sort ----------
__global__ void k_sortw(const int* __restrict__ rowptr, int* __restrict__ edge_ids) {
    int gw = (blockIdx.x * 256 + threadIdx.x) >> 6;  // node = global wave id
    int lane = threadIdx.x & 63;
    int s = rowptr[gw], e = rowptr[gw + 1], deg = e - s;
    if (deg <= 64) {
        int v = (lane < deg) ? edge_ids[s + lane] : 0x7fffffff;
        int rank = 0;
#pragma unroll
        for (int j = 0; j < 64; ++j) {
            int vj = __shfl(v, j, 64);
            rank += (vj < v) ? 1 : 0;
        }
        if (lane < deg) edge_ids[s + rank] = v;
    } else if (lane == 0) {
        for (int i = s + 1; i < e; ++i) {
            int v = edge_ids[i];
            int j = i - 1;
            while (j >= s && edge_ids[j] > v) { edge_ids[j + 1] = edge_ids[j]; --j; }
            edge_ids[j + 1] = v;
        }
    }
}

// ---------- pe[l,e,h] = dot(ef[src,trg,:], wsum[l,h,:]) ; one wave per edge ----------
__global__ void k_pe(const float* __restrict__ ef, const int* __restrict__ src,
                     const int* __restrict__ trg, const float* __restrict__ wsum,
                     float* __restrict__ pe) {
    __shared__ float wl[2 * HH * CC];
    int t = threadIdx.x;
    for (int i = t; i < 2 * HH * CC; i += 256) wl[i] = wsum[i];
    __syncthreads();
    int wid = t >> 6, lane = t & 63;
    int e = blockIdx.x * 4 + wid;
    int s = src[e], g = trg[e];
    const float* row = ef + ((long)s * NN + g) * CC;
    float4 v = *(const float4*)(row + lane * 4);
    float acc[8];
#pragma unroll
    for (int i = 0; i < 8; ++i) {
        const float* w = wl + i * CC + lane * 4;
        acc[i] = v.x * w[0] + v.y * w[1] + v.z * w[2] + v.w * w[3];
    }
#pragma unroll
    for (int off = 32; off; off >>= 1)
#pragma unroll
        for (int i = 0; i < 8; ++i) acc[i] += __shfl_down(acc[i], off, 64);
    if (lane == 0) {
#pragma unroll
        for (int i = 0; i < 8; ++i) {
            int l = i >> 2, h = i & 3;
            pe[(size_t)l * EE * HH + (size_t)e * HH + h] = acc[i];
        }
    }
}

// ---------- node projection + per-node attention dots ----------
#define ROWS 8
__global__ void k_proj(const float* __restrict__ x, const float* __restrict__ WT,
                       const float* __restrict__ a_s, const float* __restrict__ a_t,
                       float* __restrict__ hout, float* __restrict__ alpha_s,
                       float* __restrict__ alpha_t) {
    __shared__ float xs[ROWS][CC];
    int t = threadIdx.x;
    int r0 = blockIdx.x * ROWS;
    for (int j = 0; j < ROWS; ++j) xs[j][t] = x[(size_t)(r0 + j) * CC + t];
    __syncthreads();
    float acc[ROWS];
#pragma unroll
    for (int j = 0; j < ROWS; ++j) acc[j] = 0.f;
    for (int c = 0; c < CC; ++c) {
        float w = WT[c * CC + t];
#pragma unroll
        for (int j = 0; j < ROWS; ++j) acc[j] += w * xs[j][c];
    }
    int h = t >> 6, d = t & 63;
    float as = a_s[h * DD + d], at = a_t[h * DD + d];
    for (int j = 0; j < ROWS; ++j) {
        hout[(size_t)(r0 + j) * CC + t] = acc[j];
        float vs = acc[j] * as, vt = acc[j] * at;
#pragma unroll
        for (int off = 32; off; off >>= 1) {
            vs += __shfl_down(vs, off, 64);
            vt += __shfl_down(vt, off, 64);
        }
        if (d == 0) {
            alpha_s[(size_t)(r0 + j) * HH + h] = vs;
            alpha_t[(size_t)(r0 + j) * HH + h] = vt;
        }
    }
}

// ---------- single-pass aggregation: block=(n,b), 4 waves split the edges ----------
__global__ void k_agg(const float* __restrict__ hbuf, const float* __restrict__ alpha_s,
                      const float* __restrict__ alpha_t, const float* __restrict__ pe_l,
                      const int* __restrict__ rowptr, const int* __restrict__ edge_ids,
                      const int* __restrict__ src, float* __restrict__ out) {
    __shared__ float sacc[4][CC];
    __shared__ float sden[4][HH];
    int t = threadIdx.x, w = t >> 6, lane = t & 63;
    int n = blockIdx.x >> 2, b = blockIdx.x & 3;
    int start = rowptr[n], end = rowptr[n + 1];
    int h = lane >> 4;  // head owning channels [lane*4, lane*4+4)
    float at_n = alpha_t[((size_t)n * BB + b) * HH + h];
    float ax = 0.f, ay = 0.f, az = 0.f, aw = 0.f, den = 0.f;
    for (int i = start + w; i < end; i += 4) {
        int e = edge_ids[i];
        int s = src[e];
        float sc = alpha_s[((size_t)s * BB + b) * HH + h] + at_n + pe_l[(size_t)e * HH + h];
        sc = sc > 0.f ? sc : 0.2f * sc;
        float ex = __expf(sc);
        float4 v = *(const float4*)(hbuf + ((size_t)s * BB + b) * CC + lane * 4);
        ax += ex * v.x; ay += ex * v.y; az += ex * v.z; aw += ex * v.w;
        den += ex;
    }
    ((float4*)sacc[w])[lane] = make_float4(ax, ay, az, aw);
    if ((lane & 15) == 0) sden[w][h] = den;
    __syncthreads();
    float tot = sacc[0][t] + sacc[1][t] + sacc[2][t] + sacc[3][t];
    int th = t >> 6;
    float d = sden[0][th] + sden[1][th] + sden[2][th] + sden[3][th];
    out[((size_t)n * BB + b) * CC + t] = tot / (d + 1e-16f);
}

// ---------- launch ----------
extern "C" void kernel_launch(void* const* d_in, const int* in_sizes, int n_in,
                              void* d_out, int out_size, void* d_ws, size_t ws_size,
                              hipStream_t stream) {
    const float* x   = (const float*)d_in[0];
    const float* ef  = (const float*)d_in[1];
    const int* src   = (const int*)d_in[2];
    const int* trg   = (const int*)d_in[3];
    const float* Wn1 = (const float*)d_in[4];
    const float* We1 = (const float*)d_in[5];
    const float* as1 = (const float*)d_in[6];
    const float* at1 = (const float*)d_in[7];
    const float* ae1 = (const float*)d_in[8];
    const float* Wn2 = (const float*)d_in[9];
    const float* We2 = (const float*)d_in[10];
    const float* as2 = (const float*)d_in[11];
    const float* at2 = (const float*)d_in[12];
    const float* ae2 = (const float*)d_in[13];
    float* out = (float*)d_out;

    float* wsf = (float*)d_ws;
    float* WnT1   = wsf;                    // 65536
    float* WnT2   = wsf + 65536;            // 65536
    float* wsum   = wsf + 131072;           // 2048
    float* pe     = wsf + 133120;           // 2*E*H = 262144
    float* hbuf   = wsf + 395264;           // N*B*C = 1048576
    float* alphas = wsf + 1443840;          // 16384
    float* alphat = wsf + 1460224;          // 16384
    float* x1     = wsf + 1476608;          // 1048576
    int*   iws    = (int*)(wsf + 2525184);
    int* rowptr   = iws;                    // N+1
    int* edge_ids = iws + 1040;             // E

    k_prep<<<520, 256, 0, stream>>>(Wn1, Wn2, WnT1, WnT2, We1, ae1, We2, ae2, wsum);
    k_scanfill<<<1, NN, 0, stream>>>(trg, rowptr, edge_ids);
    k_sortw<<<NN / 4, 256, 0, stream>>>(rowptr, edge_ids);
    k_pe<<<EE / 4, 256, 0, stream>>>(ef, src, trg, wsum, pe);

    // layer 1
    k_proj<<<(NN * BB) / ROWS, CC, 0, stream>>>(x, WnT1, as1, at1, hbuf, alphas, alphat);
    k_agg<<<NN * BB, 256, 0, stream>>>(hbuf, alphas, alphat, pe, rowptr, edge_ids, src, x1);
    // layer 2
    k_proj<<<(NN * BB) / ROWS, CC, 0, stream>>>(x1, WnT2, as2, at2, hbuf, alphas, alphat);
    k_agg<<<NN * BB, 256, 0, stream>>>(hbuf, alphas, alphat, pe + (size_t)EE * HH,
                                       rowptr, edge_ids, src, out);
}

// Round 4
// 118.831 us; speedup vs baseline: 3.2000x; 1.2576x over previous
//
#include <hip/hip_runtime.h>
#include <cstdint>
#include <cstddef>

#define NN 1024
#define BB 4
#define CC 256
#define HH 4
#define DD 64
#define EE 32768
#define ROWS 8

// ================= device bodies =================

// node projection: h = x @ Wn.T (via WT), fused per-node attention dots.
// x rows are read via wave-uniform addresses -> scalar loads (s_load), no LDS.
__device__ __forceinline__ void proj_body(const float* __restrict__ x,
                                          const float* __restrict__ WT,
                                          const float* __restrict__ a_s,
                                          const float* __restrict__ a_t,
                                          float* __restrict__ hout,
                                          float* __restrict__ alpha_s,
                                          float* __restrict__ alpha_t,
                                          int bid, int t) {
    int r0 = bid * ROWS;
    const float* xr = x + (size_t)r0 * CC;
    float acc[ROWS];
#pragma unroll
    for (int j = 0; j < ROWS; ++j) acc[j] = 0.f;
#pragma unroll 4
    for (int c = 0; c < CC; ++c) {
        float w = WT[c * CC + t];
#pragma unroll
        for (int j = 0; j < ROWS; ++j) acc[j] += w * xr[(size_t)j * CC + c];
    }
    int h = t >> 6, d = t & 63;
    float as = a_s[h * DD + d], at = a_t[h * DD + d];
#pragma unroll
    for (int j = 0; j < ROWS; ++j) {
        hout[(size_t)(r0 + j) * CC + t] = acc[j];
        float vs = acc[j] * as, vt = acc[j] * at;
#pragma unroll
        for (int off = 32; off; off >>= 1) {
            vs += __shfl_down(vs, off, 64);
            vt += __shfl_down(vt, off, 64);
        }
        if (d == 0) {
            alpha_s[(size_t)(r0 + j) * HH + h] = vs;
            alpha_t[(size_t)(r0 + j) * HH + h] = vt;
        }
    }
}

// ================= L1: transposes + wsum + CSR scanfill =================
// grid 131 x 1024:
//   bid 0..63   : transpose Wn1
//   bid 64..127 : transpose Wn2
//   bid 128,129 : wsum layer (bid-128)
//   bid 130     : count+scan+fill (single block)
__global__ void k_L1(const float* __restrict__ Wn1, const float* __restrict__ Wn2,
                     float* __restrict__ WnT1, float* __restrict__ WnT2,
                     const float* __restrict__ We1, const float* __restrict__ ae1,
                     const float* __restrict__ We2, const float* __restrict__ ae2,
                     float* __restrict__ wsum, const int* __restrict__ trg,
                     int* __restrict__ rowptr, int* __restrict__ edge_ids) {
    __shared__ int cnt[NN];
    __shared__ int pos[NN];
    int bid = blockIdx.x, t = threadIdx.x;
    if (bid < 64) {
        int e = bid * 1024 + t;
        WnT1[(e & 255) * CC + (e >> 8)] = Wn1[e];
    } else if (bid < 128) {
        int e = (bid - 64) * 1024 + t;
        WnT2[(e & 255) * CC + (e >> 8)] = Wn2[e];
    } else if (bid < 130) {
        int l = bid - 128;
        const float* We = l ? We2 : We1;
        const float* ae = l ? ae2 : ae1;
        int c = t & 255, h = t >> 8;
        float s = 0.f;
        for (int d = 0; d < DD; ++d) s += We[(h * DD + d) * CC + c];
        wsum[(l * HH + h) * CC + c] = s * ae[h];
    } else {
        cnt[t] = 0;
        __syncthreads();
        for (int e = t; e < EE; e += NN) atomicAdd(&cnt[trg[e]], 1);
        __syncthreads();
        for (int off = 1; off < NN; off <<= 1) {
            int v = (t >= off) ? cnt[t - off] : 0;
            __syncthreads();
            cnt[t] += v;
            __syncthreads();
        }
        int excl = (t == 0) ? 0 : cnt[t - 1];
        rowptr[t] = excl;
        pos[t] = excl;
        if (t == NN - 1) rowptr[NN] = cnt[NN - 1];
        __syncthreads();
        for (int e = t; e < EE; e += NN) {
            int p = atomicAdd(&pos[trg[e]], 1);
            edge_ids[p] = e;
        }
    }
}

// ================= L2: proj(layer1) + pe + sortw =================
// grid 8960 x 256:
//   bid 0..511     : proj layer 1
//   bid 512..8703  : pe (4 edges per block, both layers)
//   bid 8704..8959 : sortw (4 nodes per block)
__global__ void k_L2(const float* __restrict__ x, const float* __restrict__ WnT1,
                     const float* __restrict__ as1, const float* __restrict__ at1,
                     float* __restrict__ hbuf, float* __restrict__ alpha_s,
                     float* __restrict__ alpha_t,
                     const float* __restrict__ ef, const int* __restrict__ src,
                     const int* __restrict__ trg, const float* __restrict__ wsum,
                     float* __restrict__ pe,
                     const int* __restrict__ rowptr, int* __restrict__ edge_ids) {
    __shared__ float wl[2 * HH * CC];
    int bid = blockIdx.x, t = threadIdx.x;
    if (bid < 512) {
        proj_body(x, WnT1, as1, at1, hbuf, alpha_s, alpha_t, bid, t);
    } else if (bid < 8704) {
        for (int i = t; i < 2 * HH * CC; i += 256) wl[i] = wsum[i];
        __syncthreads();
        int wid = t >> 6, lane = t & 63;
        int e = (bid - 512) * 4 + wid;
        int s = src[e], g = trg[e];
        const float* row = ef + ((long)s * NN + g) * CC;
        float4 v = *(const float4*)(row + lane * 4);
        float acc[8];
#pragma unroll
        for (int i = 0; i < 8; ++i) {
            const float* w = wl + i * CC + lane * 4;
            acc[i] = v.x * w[0] + v.y * w[1] + v.z * w[2] + v.w * w[3];
        }
#pragma unroll
        for (int off = 32; off; off >>= 1)
#pragma unroll
            for (int i = 0; i < 8; ++i) acc[i] += __shfl_down(acc[i], off, 64);
        if (lane == 0) {
#pragma unroll
            for (int i = 0; i < 8; ++i) {
                int l = i >> 2, h = i & 3;
                pe[(size_t)l * EE * HH + (size_t)e * HH + h] = acc[i];
            }
        }
    } else {
        int lane = t & 63;
        int n = (bid - 8704) * 4 + (t >> 6);
        int s = rowptr[n], e = rowptr[n + 1], deg = e - s;
        if (deg <= 64) {
            int v = (lane < deg) ? edge_ids[s + lane] : 0x7fffffff;
            int rank = 0;
#pragma unroll
            for (int j = 0; j < 64; ++j) {
                int vj = __shfl(v, j, 64);
                rank += (vj < v) ? 1 : 0;
            }
            if (lane < deg) edge_ids[s + rank] = v;
        } else if (lane == 0) {
            for (int i = s + 1; i < e; ++i) {
                int v = edge_ids[i];
                int j = i - 1;
                while (j >= s && edge_ids[j] > v) { edge_ids[j + 1] = edge_ids[j]; --j; }
                edge_ids[j + 1] = v;
            }
        }
    }
}

// ================= standalone proj (layer 2) =================
__global__ void k_proj(const float* __restrict__ x, const float* __restrict__ WT,
                       const float* __restrict__ a_s, const float* __restrict__ a_t,
                       float* __restrict__ hout, float* __restrict__ alpha_s,
                       float* __restrict__ alpha_t) {
    proj_body(x, WT, a_s, a_t, hout, alpha_s, alpha_t, blockIdx.x, threadIdx.x);
}

// ================= aggregation =================
__global__ void k_agg(const float* __restrict__ hbuf, const float* __restrict__ alpha_s,
                      const float* __restrict__ alpha_t, const float* __restrict__ pe_l,
                      const int* __restrict__ rowptr, const int* __restrict__ edge_ids,
                      const int* __restrict__ src, float* __restrict__ out) {
    __shared__ float sacc[4][CC];
    __shared__ float sden[4][HH];
    int t = threadIdx.x, w = t >> 6, lane = t & 63;
    int n = blockIdx.x >> 2, b = blockIdx.x & 3;
    int start = rowptr[n], end = rowptr[n + 1];
    int h = lane >> 4;
    float at_n = alpha_t[((size_t)n * BB + b) * HH + h];
    float ax = 0.f, ay = 0.f, az = 0.f, aw = 0.f, den = 0.f;
#pragma unroll 2
    for (int i = start + w; i < end; i += 4) {
        int e = edge_ids[i];
        int s = src[e];
        float sc = alpha_s[((size_t)s * BB + b) * HH + h] + at_n + pe_l[(size_t)e * HH + h];
        sc = sc > 0.f ? sc : 0.2f * sc;
        float ex = __expf(sc);
        float4 v = *(const float4*)(hbuf + ((size_t)s * BB + b) * CC + lane * 4);
        ax += ex * v.x; ay += ex * v.y; az += ex * v.z; aw += ex * v.w;
        den += ex;
    }
    ((float4*)sacc[w])[lane] = make_float4(ax, ay, az, aw);
    if ((lane & 15) == 0) sden[w][h] = den;
    __syncthreads();
    float tot = sacc[0][t] + sacc[1][t] + sacc[2][t] + sacc[3][t];
    int th = t >> 6;
    float d = sden[0][th] + sden[1][th] + sden[2][th] + sden[3][th];
    out[((size_t)n * BB + b) * CC + t] = tot / (d + 1e-16f);
}

// ================= launch =================
extern "C" void kernel_launch(void* const* d_in, const int* in_sizes, int n_in,
                              void* d_out, int out_size, void* d_ws, size_t ws_size,
                              hipStream_t stream) {
    const float* x   = (const float*)d_in[0];
    const float* ef  = (const float*)d_in[1];
    const int* src   = (const int*)d_in[2];
    const int* trg   = (const int*)d_in[3];
    const float* Wn1 = (const float*)d_in[4];
    const float* We1 = (const float*)d_in[5];
    const float* as1 = (const float*)d_in[6];
    const float* at1 = (const float*)d_in[7];
    const float* ae1 = (const float*)d_in[8];
    const float* Wn2 = (const float*)d_in[9];
    const float* We2 = (const float*)d_in[10];
    const float* as2 = (const float*)d_in[11];
    const float* at2 = (const float*)d_in[12];
    const float* ae2 = (const float*)d_in[13];
    float* out = (float*)d_out;

    float* wsf = (float*)d_ws;
    float* WnT1   = wsf;                    // 65536
    float* WnT2   = wsf + 65536;            // 65536
    float* wsum   = wsf + 131072;           // 2048
    float* pe     = wsf + 133120;           // 2*E*H = 262144
    float* hbuf   = wsf + 395264;           // N*B*C = 1048576
    float* alphas = wsf + 1443840;          // 16384
    float* alphat = wsf + 1460224;          // 16384
    float* x1     = wsf + 1476608;          // 1048576
    int*   iws    = (int*)(wsf + 2525184);
    int* rowptr   = iws;                    // N+1
    int* edge_ids = iws + 1040;             // E

    k_L1<<<131, 1024, 0, stream>>>(Wn1, Wn2, WnT1, WnT2, We1, ae1, We2, ae2,
                                   wsum, trg, rowptr, edge_ids);
    k_L2<<<8960, 256, 0, stream>>>(x, WnT1, as1, at1, hbuf, alphas, alphat,
                                   ef, src, trg, wsum, pe, rowptr, edge_ids);
    k_agg<<<NN * BB, 256, 0, stream>>>(hbuf, alphas, alphat, pe, rowptr, edge_ids, src, x1);
    k_proj<<<(NN * BB) / ROWS, 256, 0, stream>>>(x1, WnT2, as2, at2, hbuf, alphas, alphat);
    k_agg<<<NN * BB, 256, 0, stream>>>(hbuf, alphas, alphat, pe + (size_t)EE * HH,
                                       rowptr, edge_ids, src, out);
}